// Round 2
// baseline (122.696 us; speedup 1.0000x reference)
//
#include <hip/hip_runtime.h>
#include <hip/hip_bf16.h>

#define B_TOT  1024
#define IN_DIM 512
#define C_DIM  128
#define HID    128
#define EMB    32
#define BM     128
#define BK     64
#define NKT    (IN_DIM / BK)   // 8

using bf16x8 = __attribute__((ext_vector_type(8))) short;
using f32x4  = __attribute__((ext_vector_type(4))) float;

__device__ __forceinline__ unsigned short f2b(float f) {
    union { __hip_bfloat16 h; unsigned short u; } cv;
    cv.h = __float2bfloat16(f);
    return cv.u;
}
__device__ __forceinline__ unsigned int pack2(float a, float b) {
    return (unsigned int)f2b(a) | ((unsigned int)f2b(b) << 16);
}
__device__ __forceinline__ unsigned long long pack4(float a, float b, float c, float d) {
    return (unsigned long long)pack2(a, b) | ((unsigned long long)pack2(c, d) << 32);
}
__device__ __forceinline__ bf16x8 ld16(const unsigned short* p) {
    return *(const bf16x8*)p;   // 16B-aligned by construction
}

// LDS map (dynamic, 163840 B total):
//  W1T: smem[0 .. 65536)  ushorts: elem (h,k) at h*512 + ((kg^(h&7))<<3) + (k&7), kg=k>>3
//  U  : smem[65536 .. 81920) ushorts (32 KB), time-multiplexed:
//    - W2 staging (kernel start):    [e][h] flat: e*128 + h
//    - Xs double buffer (K-loop):    buf*8192 + r*64  + ((kg^(r&7))<<3) + (k&7), kg=k>>3 (0..7)
//    - Hs (epilogue1/GEMM2):         r*128 + ((kg^(r&7))<<3) + (h&7),  kg=h>>3 (0..15)

__global__ __launch_bounds__(256, 1) void bank_fused(
    const float* __restrict__ x,
    const float* __restrict__ pW1, const float* __restrict__ pb1,
    const float* __restrict__ pW2, const float* __restrict__ pb2,
    const float* __restrict__ nW1, const float* __restrict__ nb1,
    const float* __restrict__ nW2, const float* __restrict__ nb2,
    float* __restrict__ out)
{
    extern __shared__ unsigned short smem[];
    unsigned short* const W1T = smem;           // 128 KB
    unsigned short* const U   = smem + 65536;   // 32 KB

    // one block per (c, bank); xcd = c>>4 so each output 64B line (16 c's)
    // is produced entirely within one XCD (write merge), and x/W1 are
    // L2-local per XCD.
    const int p    = blockIdx.x;
    const int xcd  = p & 7;
    const int rank = p >> 3;              // 0..31
    const int c    = xcd * 16 + (rank & 15);
    const int bank = rank >> 4;

    const float* W1c = (bank ? nW1 : pW1) + (size_t)c * IN_DIM * HID;
    const float* b1c = (bank ? nb1 : pb1) + c * HID;
    const float* W2c = (bank ? nW2 : pW2) + (size_t)c * HID * EMB;
    const float* b2c = (bank ? nb2 : pb2) + c * EMB;
    float* outb = out + (size_t)bank * B_TOT * EMB * C_DIM;

    const int t    = threadIdx.x;
    const int wave = t >> 6;
    const int lane = t & 63;
    const int lr   = lane & 15;
    const int lkg  = lane >> 4;
    const int wm   = wave >> 1;
    const int wn   = wave & 1;

    // ---- stage W2 -> U (flat [e][h]), then pull fragments to registers ----
    {
        int eg = t & 7, hg = t >> 3;          // e0=4*eg (0..28), h0=4*hg (0..124)
        int e0 = eg * 4, h0 = hg * 4;
        const float* src = &W2c[(size_t)h0 * EMB + e0];
        f32x4 L0 = *(const f32x4*)(src + 0 * EMB);
        f32x4 L1 = *(const f32x4*)(src + 1 * EMB);
        f32x4 L2 = *(const f32x4*)(src + 2 * EMB);
        f32x4 L3 = *(const f32x4*)(src + 3 * EMB);
#pragma unroll
        for (int j = 0; j < 4; ++j)
            *(unsigned long long*)&U[(e0 + j) * 128 + h0] =
                pack4(L0[j], L1[j], L2[j], L3[j]);
    }
    __syncthreads();
    bf16x8 w2f[2][4];
#pragma unroll
    for (int ei = 0; ei < 2; ++ei)
#pragma unroll
        for (int k2 = 0; k2 < 4; ++k2)
            w2f[ei][k2] = ld16(&U[(ei * 16 + lr) * 128 + k2 * 32 + lkg * 8]);
    float b1v[4];
#pragma unroll
    for (int ni = 0; ni < 4; ++ni) b1v[ni] = b1c[wn * 64 + ni * 16 + lr];
    float b2v[2];
#pragma unroll
    for (int ei = 0; ei < 2; ++ei) b2v[ei] = b2c[ei * 16 + lr];
    __syncthreads();   // U free for Xs/Hs

    // ======================= btile loop (8 x 128 rows) =======================
    for (int bt = 0; bt < 8; ++bt) {
        const int bbase = bt * BM;

        f32x4 acc[4][4];
#pragma unroll
        for (int mi = 0; mi < 4; ++mi)
#pragma unroll
            for (int ni = 0; ni < 4; ++ni) acc[mi][ni] = (f32x4){0.f, 0.f, 0.f, 0.f};

        // --- prologue: stage X tile 0 (and, on bt==0, W1 chunk 0) ---
        {
#pragma unroll
            for (int w8 = 0; w8 < 8; ++w8) {
                int f = w8 * 256 + t;
                int row = f >> 4, colq = (f & 15) * 4;
                f32x4 v = *(const f32x4*)&x[(size_t)(bbase + row) * IN_DIM + colq];
                int kg = colq >> 3, kin = colq & 7;
                *(unsigned long long*)&U[row * 64 + (((kg) ^ (row & 7)) << 3) + kin] =
                    pack4(v[0], v[1], v[2], v[3]);
            }
            if (bt == 0) {
#pragma unroll
                for (int g = 0; g < 2; ++g) {
                    int s = g * 256 + t;
                    int h0 = (s & 31) * 4;
                    int k0 = (s >> 5) * 4;       // 0..60 within chunk 0
                    const float* src = &W1c[(size_t)k0 * HID + h0];
                    f32x4 L0 = *(const f32x4*)(src + 0 * HID);
                    f32x4 L1 = *(const f32x4*)(src + 1 * HID);
                    f32x4 L2 = *(const f32x4*)(src + 2 * HID);
                    f32x4 L3 = *(const f32x4*)(src + 3 * HID);
                    int kg = k0 >> 3, kin = k0 & 7;
#pragma unroll
                    for (int j = 0; j < 4; ++j) {
                        int h = h0 + j;
                        *(unsigned long long*)&W1T[h * 512 + ((kg ^ (h & 7)) << 3) + kin] =
                            pack4(L0[j], L1[j], L2[j], L3[j]);
                    }
                }
            }
        }
        __syncthreads();

        // --- K loop: single barrier per step, reg-prefetch next tiles ---
        unsigned cur = 0;
        for (int kt = 0; kt < NKT; ++kt) {
            // 1) issue next-tile global loads (hidden under MFMA)
            f32x4 xp[8];
            f32x4 wp[2][4];
            const bool pre = (kt < NKT - 1);
            if (pre) {
                int kb = (kt + 1) * BK;
#pragma unroll
                for (int w8 = 0; w8 < 8; ++w8) {
                    int f = w8 * 256 + t;
                    int row = f >> 4, colq = (f & 15) * 4;
                    xp[w8] = *(const f32x4*)&x[(size_t)(bbase + row) * IN_DIM + kb + colq];
                }
                if (bt == 0) {
#pragma unroll
                    for (int g = 0; g < 2; ++g) {
                        int s = g * 256 + t;
                        int h0 = (s & 31) * 4;
                        int k0 = kb + (s >> 5) * 4;
                        const float* src = &W1c[(size_t)k0 * HID + h0];
                        wp[g][0] = *(const f32x4*)(src + 0 * HID);
                        wp[g][1] = *(const f32x4*)(src + 1 * HID);
                        wp[g][2] = *(const f32x4*)(src + 2 * HID);
                        wp[g][3] = *(const f32x4*)(src + 3 * HID);
                    }
                }
            }

            // 2) MFMA on current buffers
            const unsigned short* Xb = &U[cur * 8192];
#pragma unroll
            for (int ki = 0; ki < 2; ++ki) {
                bf16x8 af[4], bfr[4];
                int kg = ki * 4 + lkg;                 // 0..7 within X tile
                int kgW = kt * 8 + ki * 4 + lkg;       // 0..63 in W1T
#pragma unroll
                for (int mi = 0; mi < 4; ++mi) {
                    int r = wm * 64 + mi * 16 + lr;
                    af[mi] = ld16(&Xb[r * 64 + ((kg ^ (r & 7)) << 3)]);
                }
#pragma unroll
                for (int ni = 0; ni < 4; ++ni) {
                    int h = wn * 64 + ni * 16 + lr;
                    bfr[ni] = ld16(&W1T[h * 512 + ((kgW ^ (h & 7)) << 3)]);
                }
#pragma unroll
                for (int mi = 0; mi < 4; ++mi)
#pragma unroll
                    for (int ni = 0; ni < 4; ++ni)
                        acc[mi][ni] = __builtin_amdgcn_mfma_f32_16x16x32_bf16(
                            af[mi], bfr[ni], acc[mi][ni], 0, 0, 0);
            }

            // 3) write prefetched tiles (other Xs buffer / future W1T range)
            if (pre) {
#pragma unroll
                for (int w8 = 0; w8 < 8; ++w8) {
                    int f = w8 * 256 + t;
                    int row = f >> 4, colq = (f & 15) * 4;
                    int kg = colq >> 3, kin = colq & 7;
                    *(unsigned long long*)&U[(cur ^ 1) * 8192 + row * 64 +
                                             ((kg ^ (row & 7)) << 3) + kin] =
                        pack4(xp[w8][0], xp[w8][1], xp[w8][2], xp[w8][3]);
                }
                if (bt == 0) {
                    int kb = (kt + 1) * BK;
#pragma unroll
                    for (int g = 0; g < 2; ++g) {
                        int s = g * 256 + t;
                        int h0 = (s & 31) * 4;
                        int k0 = kb + (s >> 5) * 4;
                        int kg = k0 >> 3, kin = k0 & 7;
#pragma unroll
                        for (int j = 0; j < 4; ++j) {
                            int h = h0 + j;
                            *(unsigned long long*)&W1T[h * 512 + ((kg ^ (h & 7)) << 3) + kin] =
                                pack4(wp[g][0][j], wp[g][1][j], wp[g][2][j], wp[g][3][j]);
                        }
                    }
                }
            }
            __syncthreads();
            cur ^= 1;
        }

        // --- epilogue1: bias + relu -> Hs (over Xs buffers; all reads done) ---
#pragma unroll
        for (int mi = 0; mi < 4; ++mi) {
            int row0 = wm * 64 + mi * 16 + lkg * 4;
#pragma unroll
            for (int ni = 0; ni < 4; ++ni) {
                int col = wn * 64 + ni * 16 + lr;
                int kgH = col >> 3, kin = col & 7;
#pragma unroll
                for (int j = 0; j < 4; ++j) {
                    int r = row0 + j;
                    float v = fmaxf(acc[mi][ni][j] + b1v[ni], 0.f);
                    U[r * 128 + ((kgH ^ (r & 7)) << 3) + kin] = f2b(v);
                }
            }
        }
        __syncthreads();

        // --- GEMM2: out = Hs * W2 + b2 (M=128, N=32, K=128) ---
        f32x4 acc2[2][2];
#pragma unroll
        for (int m2 = 0; m2 < 2; ++m2)
#pragma unroll
            for (int ei = 0; ei < 2; ++ei) acc2[m2][ei] = (f32x4){0.f, 0.f, 0.f, 0.f};

        const int rb = wave * 32;
#pragma unroll
        for (int k2 = 0; k2 < 4; ++k2) {
            bf16x8 a2[2];
            int kg = k2 * 4 + lkg;   // 0..15
#pragma unroll
            for (int m2 = 0; m2 < 2; ++m2) {
                int r = rb + m2 * 16 + lr;
                a2[m2] = ld16(&U[r * 128 + ((kg ^ (r & 7)) << 3)]);
            }
#pragma unroll
            for (int m2 = 0; m2 < 2; ++m2)
#pragma unroll
                for (int ei = 0; ei < 2; ++ei)
                    acc2[m2][ei] = __builtin_amdgcn_mfma_f32_16x16x32_bf16(
                        a2[m2], w2f[ei][k2], acc2[m2][ei], 0, 0, 0);
        }

        // --- stores: out[b][e][c], fp32; merges in this XCD's L2 ---
#pragma unroll
        for (int m2 = 0; m2 < 2; ++m2) {
#pragma unroll
            for (int ei = 0; ei < 2; ++ei) {
                int e = ei * 16 + lr;
#pragma unroll
                for (int j = 0; j < 4; ++j) {
                    int brow = bbase + rb + m2 * 16 + lkg * 4 + j;
                    outb[((size_t)brow * EMB + e) * C_DIM + c] = acc2[m2][ei][j] + b2v[ei];
                }
            }
        }
        __syncthreads();   // Hs reads done before next btile's Xs staging
    }
}

extern "C" void kernel_launch(void* const* d_in, const int* in_sizes, int n_in,
                              void* d_out, int out_size, void* d_ws, size_t ws_size,
                              hipStream_t stream) {
    const float* x   = (const float*)d_in[0];
    const float* pW1 = (const float*)d_in[1];
    const float* pb1 = (const float*)d_in[2];
    const float* pW2 = (const float*)d_in[3];
    const float* pb2 = (const float*)d_in[4];
    const float* nW1 = (const float*)d_in[5];
    const float* nb1 = (const float*)d_in[6];
    const float* nW2 = (const float*)d_in[7];
    const float* nb2 = (const float*)d_in[8];
    float* out = (float*)d_out;

    (void)hipFuncSetAttribute((const void*)bank_fused,
                              hipFuncAttributeMaxDynamicSharedMemorySize, 163840);
    bank_fused<<<dim3(256), dim3(256), 163840, stream>>>(
        x, pW1, pb1, pW2, pb2, nW1, nb1, nW2, nb2, out);
}